// Round 1
// baseline (520.825 us; speedup 1.0000x reference)
//
#include <hip/hip_runtime.h>
#include <math.h>

typedef unsigned int u32;
typedef unsigned short u16;
typedef short bf16x8 __attribute__((ext_vector_type(8)));
typedef unsigned short u16x8 __attribute__((ext_vector_type(8)));
typedef float f32x4 __attribute__((ext_vector_type(4)));

#define SEQ 2048
#define NH 16
#define HD 64
#define DM 1024
#define MROWS 8192   // 4*2048

static __device__ __forceinline__ u16 f2bf(float f) {
  u32 u = __builtin_bit_cast(u32, f);
  u32 r = (u + 0x7FFFu + ((u >> 16) & 1u)) >> 16;
  return (u16)r;
}

#define GLDS16(gsrc, ldst)                                                        \
  __builtin_amdgcn_global_load_lds(                                               \
      (const __attribute__((address_space(1))) void*)(gsrc),                      \
      (__attribute__((address_space(3))) void*)(ldst), 16, 0, 0)

// ---------------- prep kernels ----------------
__global__ void cast_bf16_kernel(const float* __restrict__ src, u16* __restrict__ dst, int n) {
  int i = (blockIdx.x * blockDim.x + threadIdx.x) * 4;
  if (i >= n) return;
  float4 v = *reinterpret_cast<const float4*>(src + i);
  ushort4 o;
  o.x = f2bf(v.x); o.y = f2bf(v.y); o.z = f2bf(v.z); o.w = f2bf(v.w);
  *reinterpret_cast<ushort4*>(dst + i) = o;
}

__global__ void rope_table_kernel(float* __restrict__ ct, float* __restrict__ st) {
  int t = blockIdx.x * blockDim.x + threadIdx.x;  // 0..65535
  int s = t >> 5, i = t & 31;
  double theta_d = pow(10000.0, -(double)i / 32.0);
  float th = (float)theta_d;          // matches f32 theta in reference
  float fr = (float)s * th;           // f32 multiply like numpy
  ct[t] = (float)cos((double)fr);
  st[t] = (float)sin((double)fr);
}

// ---------------- GEMM template ----------------
// C[m][n] = sum_k A[m][k]*B[n][k]  (both k-major, K=1024), 128x128 tile, BK=64
// EPI 0: +bias, RoPE, scatter q->Qw[b,h,s,d], k->Kw[b,h,s,d], v->Vt[b,h,d,s]
// EPI 1: +bias, fp32 out [m][n]
template <int EPI>
__global__ __launch_bounds__(256) void gemm128(
    const u16* __restrict__ A, const u16* __restrict__ Bw,
    const float* __restrict__ bias,
    u16* __restrict__ Qo, u16* __restrict__ Ko, u16* __restrict__ Vo,
    const float* __restrict__ ct, const float* __restrict__ st,
    float* __restrict__ Co) {
  __shared__ u16 As[128 * 64];
  __shared__ u16 Bs[128 * 64];
  const int tid = threadIdx.x;
  const int lane = tid & 63;
  const int w = tid >> 6;
  const int wm = w >> 1, wn = w & 1;
  const int m0 = blockIdx.y * 128;
  const int n0 = blockIdx.x * 128;

  f32x4 acc[4][4];
#pragma unroll
  for (int i = 0; i < 4; i++)
#pragma unroll
    for (int j = 0; j < 4; j++) acc[i][j] = (f32x4){0.f, 0.f, 0.f, 0.f};

  for (int kt = 0; kt < 1024 / 64; ++kt) {
    const int k0 = kt * 64;
    __syncthreads();
#pragma unroll
    for (int c = 0; c < 4; ++c) {
      int e = ((c * 4 + w) * 64 + lane) * 8;  // elem offset in 128x64 tile
      int row = e >> 6, col = e & 63;
      GLDS16(A + (size_t)(m0 + row) * 1024 + k0 + col, &As[e]);
      GLDS16(Bw + (size_t)(n0 + row) * 1024 + k0 + col, &Bs[e]);
    }
    asm volatile("s_waitcnt vmcnt(0)" ::: "memory");
    __syncthreads();

    bf16x8 af[4][2], bfr[4][2];
#pragma unroll
    for (int i = 0; i < 4; i++) {
      int r = wm * 64 + i * 16 + (lane & 15);
#pragma unroll
      for (int kk = 0; kk < 2; kk++) {
        int kc = kk * 32 + (lane >> 4) * 8;
        af[i][kk] = *reinterpret_cast<const bf16x8*>(&As[r * 64 + kc]);
      }
    }
#pragma unroll
    for (int j = 0; j < 4; j++) {
      int r = wn * 64 + j * 16 + (lane & 15);
#pragma unroll
      for (int kk = 0; kk < 2; kk++) {
        int kc = kk * 32 + (lane >> 4) * 8;
        bfr[j][kk] = *reinterpret_cast<const bf16x8*>(&Bs[r * 64 + kc]);
      }
    }
#pragma unroll
    for (int kk = 0; kk < 2; kk++)
#pragma unroll
      for (int i = 0; i < 4; i++)
#pragma unroll
        for (int j = 0; j < 4; j++)
          acc[i][j] = __builtin_amdgcn_mfma_f32_16x16x32_bf16(af[i][kk], bfr[j][kk], acc[i][j], 0, 0, 0);
  }

  // epilogue
  if (EPI == 0) {
    const int which = n0 >> 10;  // uniform per block: 0=q 1=k 2=v
#pragma unroll
    for (int i = 0; i < 4; i++) {
#pragma unroll
      for (int j = 0; j < 4; j++) {
        int n = n0 + wn * 64 + j * 16 + (lane & 15);
        int mb = m0 + wm * 64 + i * 16 + (lane >> 4) * 4;
        float bi = bias[n];
        int d = n & 63;
        int h = (n >> 6) & 15;
        f32x4 v = acc[i][j];
#pragma unroll
        for (int r = 0; r < 4; r++) {
          int m = mb + r;
          int b = m >> 11, s = m & 2047;
          float vf = v[r] + bi;
          float pf = __shfl_xor(vf, 1, 64);  // partner column (d^1)
          float res;
          if (which < 2) {
            float c = ct[s * 32 + (d >> 1)];
            float sn = st[s * 32 + (d >> 1)];
            res = (d & 1) ? (vf * c + pf * sn) : (vf * c - pf * sn);
          } else {
            res = vf;
          }
          u16 hv = f2bf(res);
          int bh = b * 16 + h;
          if (which == 0)
            Qo[((size_t)bh * 2048 + s) * 64 + d] = hv;
          else if (which == 1)
            Ko[((size_t)bh * 2048 + s) * 64 + d] = hv;
          else
            Vo[((size_t)bh * 64 + d) * 2048 + s] = hv;  // V stored transposed [b,h,d,s]
        }
      }
    }
  } else {
#pragma unroll
    for (int i = 0; i < 4; i++) {
#pragma unroll
      for (int j = 0; j < 4; j++) {
        int n = n0 + wn * 64 + j * 16 + (lane & 15);
        int mb = m0 + wm * 64 + i * 16 + (lane >> 4) * 4;
        float bi = bias[n];
#pragma unroll
        for (int r = 0; r < 4; r++) {
          Co[(size_t)(mb + r) * 1024 + n] = acc[i][j][r] + bi;
        }
      }
    }
  }
}

// ---------------- flash attention ----------------
// grid (SEQ/64, B*NH), 256 threads (4 waves x 16 q-rows). KV tile = 64.
__global__ __launch_bounds__(256) void attn_kernel(
    const u16* __restrict__ Q, const u16* __restrict__ Kb,
    const u16* __restrict__ Vt, u16* __restrict__ AO) {
  __shared__ u16 Ks[64 * 64];
  __shared__ u16 Vs[64 * 64];   // [d][j]
  __shared__ u16 Ps[4][16 * 64];
  const int tid = threadIdx.x;
  const int lane = tid & 63;
  const int w = tid >> 6;
  const int bh = blockIdx.y;
  const int b = bh >> 4, h = bh & 15;
  const size_t base = (size_t)bh * SEQ * HD;
  const int q0 = blockIdx.x * 64 + w * 16;

  bf16x8 qf[2];
  {
    int s = q0 + (lane & 15);
#pragma unroll
    for (int kk = 0; kk < 2; kk++) {
      int d0 = kk * 32 + (lane >> 4) * 8;
      qf[kk] = *reinterpret_cast<const bf16x8*>(Q + base + (size_t)s * 64 + d0);
    }
  }

  f32x4 o[4];
#pragma unroll
  for (int dt = 0; dt < 4; dt++) o[dt] = (f32x4){0.f, 0.f, 0.f, 0.f};
  float mr[4], lr[4];
#pragma unroll
  for (int r = 0; r < 4; r++) { mr[r] = -1e30f; lr[r] = 0.f; }

  for (int t = 0; t < SEQ / 64; ++t) {
    __syncthreads();
#pragma unroll
    for (int c = 0; c < 2; ++c) {
      int e = ((c * 4 + w) * 64 + lane) * 8;
      GLDS16(Kb + base + (size_t)t * 4096 + e, &Ks[e]);
      // V^T tile: rows d (stride SEQ in global), cols j
      int d = e >> 6, j = e & 63;
      GLDS16(Vt + base + (size_t)d * 2048 + t * 64 + j, &Vs[e]);
    }
    asm volatile("s_waitcnt vmcnt(0)" ::: "memory");
    __syncthreads();

    // scores: 16 rows x 64 cols per wave
    f32x4 sc[4];
#pragma unroll
    for (int jt = 0; jt < 4; jt++) {
      f32x4 a = (f32x4){0.f, 0.f, 0.f, 0.f};
#pragma unroll
      for (int kk = 0; kk < 2; kk++) {
        int kr = jt * 16 + (lane & 15);
        int d0 = kk * 32 + (lane >> 4) * 8;
        bf16x8 kf = *reinterpret_cast<const bf16x8*>(&Ks[kr * 64 + d0]);
        a = __builtin_amdgcn_mfma_f32_16x16x32_bf16(qf[kk], kf, a, 0, 0, 0);
      }
      sc[jt] = a * 0.125f;  // 1/sqrt(64)
    }

    // online softmax (fp32)
#pragma unroll
    for (int r = 0; r < 4; r++) {
      float mx = fmaxf(fmaxf(sc[0][r], sc[1][r]), fmaxf(sc[2][r], sc[3][r]));
#pragma unroll
      for (int off = 1; off < 16; off <<= 1) mx = fmaxf(mx, __shfl_xor(mx, off, 64));
      float nm = fmaxf(mr[r], mx);
      float fs = __expf(mr[r] - nm);
      mr[r] = nm;
      float ps = 0.f;
#pragma unroll
      for (int jt = 0; jt < 4; jt++) {
        float p = __expf(sc[jt][r] - nm);
        sc[jt][r] = p;
        ps += p;
      }
#pragma unroll
      for (int off = 1; off < 16; off <<= 1) ps += __shfl_xor(ps, off, 64);
      lr[r] = lr[r] * fs + ps;
#pragma unroll
      for (int dt = 0; dt < 4; dt++) o[dt][r] *= fs;
      int row = (lane >> 4) * 4 + r;
#pragma unroll
      for (int jt = 0; jt < 4; jt++)
        Ps[w][row * 64 + jt * 16 + (lane & 15)] = f2bf(sc[jt][r]);
    }

    // PV
#pragma unroll
    for (int kk = 0; kk < 2; kk++) {
      bf16x8 pa = *reinterpret_cast<const bf16x8*>(&Ps[w][(lane & 15) * 64 + kk * 32 + (lane >> 4) * 8]);
#pragma unroll
      for (int dt = 0; dt < 4; dt++) {
        bf16x8 vf = *reinterpret_cast<const bf16x8*>(&Vs[(dt * 16 + (lane & 15)) * 64 + kk * 32 + (lane >> 4) * 8]);
        o[dt] = __builtin_amdgcn_mfma_f32_16x16x32_bf16(pa, vf, o[dt], 0, 0, 0);
      }
    }
  }

  // epilogue: AO[b][s][h*64+d] bf16
#pragma unroll
  for (int dt = 0; dt < 4; dt++) {
#pragma unroll
    for (int r = 0; r < 4; r++) {
      int srow = q0 + (lane >> 4) * 4 + r;
      float val = o[dt][r] / lr[r];
      AO[((size_t)(b * 2048 + srow)) * 1024 + h * 64 + dt * 16 + (lane & 15)] = f2bf(val);
    }
  }
}

// ---------------- launch ----------------
extern "C" void kernel_launch(void* const* d_in, const int* in_sizes, int n_in,
                              void* d_out, int out_size, void* d_ws, size_t ws_size,
                              hipStream_t stream) {
  const float* x = (const float*)d_in[0];
  const float* Wqkv = (const float*)d_in[1];
  const float* bqkv = (const float*)d_in[2];
  const float* Wout = (const float*)d_in[3];
  const float* bout = (const float*)d_in[4];
  float* out = (float*)d_out;

  char* p = (char*)d_ws;
  float* ct = (float*)p; p += (size_t)65536 * 4;
  float* st = (float*)p; p += (size_t)65536 * 4;
  u16* Xb  = (u16*)p; p += (size_t)8388608 * 2;
  u16* Wqb = (u16*)p; p += (size_t)3145728 * 2;
  u16* Wob = (u16*)p; p += (size_t)1048576 * 2;
  u16* Qw  = (u16*)p; p += (size_t)8388608 * 2;
  u16* Kw  = (u16*)p; p += (size_t)8388608 * 2;
  u16* Vw  = (u16*)p; p += (size_t)8388608 * 2;   // transposed [b,h,d,s]
  u16* AO  = (u16*)p; p += (size_t)8388608 * 2;

  cast_bf16_kernel<<<8192, 256, 0, stream>>>(x, Xb, 8388608);
  cast_bf16_kernel<<<3072, 256, 0, stream>>>(Wqkv, Wqb, 3145728);
  cast_bf16_kernel<<<1024, 256, 0, stream>>>(Wout, Wob, 1048576);
  rope_table_kernel<<<256, 256, 0, stream>>>(ct, st);

  gemm128<0><<<dim3(24, 64), 256, 0, stream>>>(Xb, Wqb, bqkv, Qw, Kw, Vw, ct, st, nullptr);
  attn_kernel<<<dim3(32, 64), 256, 0, stream>>>(Qw, Kw, Vw, AO);
  gemm128<1><<<dim3(8, 64), 256, 0, stream>>>(AO, Wob, bout, nullptr, nullptr, nullptr, nullptr, nullptr, out);
}

// Round 2
// 450.388 us; speedup vs baseline: 1.1564x; 1.1564x over previous
//
#include <hip/hip_runtime.h>
#include <math.h>

typedef unsigned int u32;
typedef unsigned short u16;
typedef short bf16x8 __attribute__((ext_vector_type(8)));
typedef unsigned short u16x8 __attribute__((ext_vector_type(8)));
typedef float f32x4 __attribute__((ext_vector_type(4)));

#define SEQ 2048
#define NH 16
#define HD 64
#define DM 1024
#define MROWS 8192   // 4*2048

static __device__ __forceinline__ u16 f2bf(float f) {
  u32 u = __builtin_bit_cast(u32, f);
  u32 r = (u + 0x7FFFu + ((u >> 16) & 1u)) >> 16;
  return (u16)r;
}

#define GLDS16(gsrc, ldst)                                                        \
  __builtin_amdgcn_global_load_lds(                                               \
      (const __attribute__((address_space(1))) void*)(gsrc),                      \
      (__attribute__((address_space(3))) void*)(ldst), 16, 0, 0)

// XOR swizzle for 64-elem-wide bf16 LDS tiles (breaks the 128B-row-stride
// bank pathology): element index (r*64+c) ^ ((r&7)*8). Involution.
static __device__ __forceinline__ int swz64(int r, int c) {
  return (r * 64 + c) ^ ((r & 7) * 8);
}

// ---------------- prep kernels ----------------
__global__ void cast_bf16_kernel(const float* __restrict__ src, u16* __restrict__ dst, int n) {
  int i = (blockIdx.x * blockDim.x + threadIdx.x) * 4;
  if (i >= n) return;
  float4 v = *reinterpret_cast<const float4*>(src + i);
  ushort4 o;
  o.x = f2bf(v.x); o.y = f2bf(v.y); o.z = f2bf(v.z); o.w = f2bf(v.w);
  *reinterpret_cast<ushort4*>(dst + i) = o;
}

__global__ void rope_table_kernel(float* __restrict__ ct, float* __restrict__ st) {
  int t = blockIdx.x * blockDim.x + threadIdx.x;  // 0..65535
  int s = t >> 5, i = t & 31;
  double theta_d = pow(10000.0, -(double)i / 32.0);
  float th = (float)theta_d;          // matches f32 theta in reference
  float fr = (float)s * th;           // f32 multiply like numpy
  ct[t] = (float)cos((double)fr);
  st[t] = (float)sin((double)fr);
}

// ---------------- GEMM template ----------------
// C[m][n] = sum_k A[m][k]*B[n][k]  (both k-major, K=1024), 128x128 tile, BK=64
// EPI 0: +bias, RoPE, scatter q->Qw[b,h,s,d], k->Kw[b,h,s,d], v->Vt[b,h,d,s]
// EPI 1: +bias, fp32 out [m][n]
template <int EPI>
__global__ __launch_bounds__(256) void gemm128(
    const u16* __restrict__ A, const u16* __restrict__ Bw,
    const float* __restrict__ bias,
    u16* __restrict__ Qo, u16* __restrict__ Ko, u16* __restrict__ Vo,
    const float* __restrict__ ct, const float* __restrict__ st,
    float* __restrict__ Co) {
  __shared__ u16 As[128 * 64];
  __shared__ u16 Bs[128 * 64];
  const int tid = threadIdx.x;
  const int lane = tid & 63;
  const int w = tid >> 6;
  const int wm = w >> 1, wn = w & 1;
  const int m0 = blockIdx.y * 128;
  const int n0 = blockIdx.x * 128;

  f32x4 acc[4][4];
#pragma unroll
  for (int i = 0; i < 4; i++)
#pragma unroll
    for (int j = 0; j < 4; j++) acc[i][j] = (f32x4){0.f, 0.f, 0.f, 0.f};

  for (int kt = 0; kt < 1024 / 64; ++kt) {
    const int k0 = kt * 64;
    __syncthreads();
#pragma unroll
    for (int c = 0; c < 4; ++c) {
      int e = ((c * 4 + w) * 64 + lane) * 8;  // elem offset in 128x64 tile
      int row = e >> 6, col = e & 63;
      GLDS16(A + (size_t)(m0 + row) * 1024 + k0 + col, &As[e]);
      GLDS16(Bw + (size_t)(n0 + row) * 1024 + k0 + col, &Bs[e]);
    }
    asm volatile("s_waitcnt vmcnt(0)" ::: "memory");
    __syncthreads();

    bf16x8 af[4][2], bfr[4][2];
#pragma unroll
    for (int i = 0; i < 4; i++) {
      int r = wm * 64 + i * 16 + (lane & 15);
#pragma unroll
      for (int kk = 0; kk < 2; kk++) {
        int kc = kk * 32 + (lane >> 4) * 8;
        af[i][kk] = *reinterpret_cast<const bf16x8*>(&As[r * 64 + kc]);
      }
    }
#pragma unroll
    for (int j = 0; j < 4; j++) {
      int r = wn * 64 + j * 16 + (lane & 15);
#pragma unroll
      for (int kk = 0; kk < 2; kk++) {
        int kc = kk * 32 + (lane >> 4) * 8;
        bfr[j][kk] = *reinterpret_cast<const bf16x8*>(&Bs[r * 64 + kc]);
      }
    }
#pragma unroll
    for (int kk = 0; kk < 2; kk++)
#pragma unroll
      for (int i = 0; i < 4; i++)
#pragma unroll
        for (int j = 0; j < 4; j++)
          acc[i][j] = __builtin_amdgcn_mfma_f32_16x16x32_bf16(af[i][kk], bfr[j][kk], acc[i][j], 0, 0, 0);
  }

  // epilogue
  if (EPI == 0) {
    const int which = n0 >> 10;  // uniform per block: 0=q 1=k 2=v
#pragma unroll
    for (int i = 0; i < 4; i++) {
#pragma unroll
      for (int j = 0; j < 4; j++) {
        int n = n0 + wn * 64 + j * 16 + (lane & 15);
        int mb = m0 + wm * 64 + i * 16 + (lane >> 4) * 4;
        float bi = bias[n];
        int d = n & 63;
        int h = (n >> 6) & 15;
        f32x4 v = acc[i][j];
#pragma unroll
        for (int r = 0; r < 4; r++) {
          int m = mb + r;
          int b = m >> 11, s = m & 2047;
          float vf = v[r] + bi;
          float pf = __shfl_xor(vf, 1, 64);  // partner column (d^1)
          float res;
          if (which < 2) {
            float c = ct[s * 32 + (d >> 1)];
            float sn = st[s * 32 + (d >> 1)];
            res = (d & 1) ? (vf * c + pf * sn) : (vf * c - pf * sn);
          } else {
            res = vf;
          }
          u16 hv = f2bf(res);
          int bh = b * 16 + h;
          if (which == 0)
            Qo[((size_t)bh * 2048 + s) * 64 + d] = hv;
          else if (which == 1)
            Ko[((size_t)bh * 2048 + s) * 64 + d] = hv;
          else
            Vo[((size_t)bh * 64 + d) * 2048 + s] = hv;  // V stored transposed [b,h,d,s]
        }
      }
    }
  } else {
#pragma unroll
    for (int i = 0; i < 4; i++) {
#pragma unroll
      for (int j = 0; j < 4; j++) {
        int n = n0 + wn * 64 + j * 16 + (lane & 15);
        int mb = m0 + wm * 64 + i * 16 + (lane >> 4) * 4;
        float bi = bias[n];
#pragma unroll
        for (int r = 0; r < 4; r++) {
          Co[(size_t)(mb + r) * 1024 + n] = acc[i][j][r] + bi;
        }
      }
    }
  }
}

// ---------------- flash attention ----------------
// grid (SEQ/64, B*NH), 256 threads (4 waves x 16 q-rows). KV tile = 64.
// All 64-wide LDS tiles XOR-swizzled (swz64). K/V are staged with
// global_load_lds (linear LDS dest) + pre-swizzled GLOBAL source address
// (the involution means source-permute == read-permute).
__global__ __launch_bounds__(256) void attn_kernel(
    const u16* __restrict__ Q, const u16* __restrict__ Kb,
    const u16* __restrict__ Vt, u16* __restrict__ AO) {
  __shared__ u16 Ks[64 * 64];
  __shared__ u16 Vs[64 * 64];   // [d][j]
  __shared__ u16 Ps[4][16 * 64];
  const int tid = threadIdx.x;
  const int lane = tid & 63;
  const int w = tid >> 6;
  const int bh = blockIdx.y;
  const int b = bh >> 4, h = bh & 15;
  const size_t base = (size_t)bh * SEQ * HD;
  const int q0 = blockIdx.x * 64 + w * 16;

  bf16x8 qf[2];
  {
    int s = q0 + (lane & 15);
#pragma unroll
    for (int kk = 0; kk < 2; kk++) {
      int d0 = kk * 32 + (lane >> 4) * 8;
      qf[kk] = *reinterpret_cast<const bf16x8*>(Q + base + (size_t)s * 64 + d0);
    }
  }

  f32x4 o[4];
#pragma unroll
  for (int dt = 0; dt < 4; dt++) o[dt] = (f32x4){0.f, 0.f, 0.f, 0.f};
  float mr[4], lr[4];
#pragma unroll
  for (int r = 0; r < 4; r++) { mr[r] = -1e30f; lr[r] = 0.f; }

  for (int t = 0; t < SEQ / 64; ++t) {
    __syncthreads();
#pragma unroll
    for (int c = 0; c < 2; ++c) {
      int e = ((c * 4 + w) * 64 + lane) * 8;   // linear LDS dest (elements)
      int se = e ^ ((lane >> 3) * 8);          // swizzled global source elem
      GLDS16(Kb + base + (size_t)t * 4096 + se, &Ks[e]);
      // V^T tile: source rows d (stride SEQ in global), cols j
      int d = se >> 6, j = se & 63;
      GLDS16(Vt + base + (size_t)d * 2048 + t * 64 + j, &Vs[e]);
    }
    asm volatile("s_waitcnt vmcnt(0)" ::: "memory");
    __syncthreads();

    // scores: 16 rows x 64 cols per wave
    f32x4 sc[4];
    __builtin_amdgcn_s_setprio(1);
#pragma unroll
    for (int jt = 0; jt < 4; jt++) {
      f32x4 a = (f32x4){0.f, 0.f, 0.f, 0.f};
#pragma unroll
      for (int kk = 0; kk < 2; kk++) {
        int kr = jt * 16 + (lane & 15);
        int d0 = kk * 32 + (lane >> 4) * 8;
        bf16x8 kf = *reinterpret_cast<const bf16x8*>(&Ks[swz64(kr, d0)]);
        a = __builtin_amdgcn_mfma_f32_16x16x32_bf16(qf[kk], kf, a, 0, 0, 0);
      }
      sc[jt] = a * 0.125f;  // 1/sqrt(64)
    }
    __builtin_amdgcn_s_setprio(0);

    // online softmax (fp32)
#pragma unroll
    for (int r = 0; r < 4; r++) {
      float mx = fmaxf(fmaxf(sc[0][r], sc[1][r]), fmaxf(sc[2][r], sc[3][r]));
#pragma unroll
      for (int off = 1; off < 16; off <<= 1) mx = fmaxf(mx, __shfl_xor(mx, off, 64));
      float nm = fmaxf(mr[r], mx);
      float fs = __expf(mr[r] - nm);
      mr[r] = nm;
      float ps = 0.f;
#pragma unroll
      for (int jt = 0; jt < 4; jt++) {
        float p = __expf(sc[jt][r] - nm);
        sc[jt][r] = p;
        ps += p;
      }
#pragma unroll
      for (int off = 1; off < 16; off <<= 1) ps += __shfl_xor(ps, off, 64);
      lr[r] = lr[r] * fs + ps;
#pragma unroll
      for (int dt = 0; dt < 4; dt++) o[dt][r] *= fs;
      int row = (lane >> 4) * 4 + r;
#pragma unroll
      for (int jt = 0; jt < 4; jt++)
        Ps[w][swz64(row, jt * 16 + (lane & 15))] = f2bf(sc[jt][r]);
    }

    // PV
    __builtin_amdgcn_s_setprio(1);
#pragma unroll
    for (int kk = 0; kk < 2; kk++) {
      int pc = kk * 32 + (lane >> 4) * 8;
      bf16x8 pa = *reinterpret_cast<const bf16x8*>(&Ps[w][swz64(lane & 15, pc)]);
#pragma unroll
      for (int dt = 0; dt < 4; dt++) {
        bf16x8 vf = *reinterpret_cast<const bf16x8*>(&Vs[swz64(dt * 16 + (lane & 15), pc)]);
        o[dt] = __builtin_amdgcn_mfma_f32_16x16x32_bf16(pa, vf, o[dt], 0, 0, 0);
      }
    }
    __builtin_amdgcn_s_setprio(0);
  }

  // epilogue: AO[b][s][h*64+d] bf16
#pragma unroll
  for (int dt = 0; dt < 4; dt++) {
#pragma unroll
    for (int r = 0; r < 4; r++) {
      int srow = q0 + (lane >> 4) * 4 + r;
      float val = o[dt][r] / lr[r];
      AO[((size_t)(b * 2048 + srow)) * 1024 + h * 64 + dt * 16 + (lane & 15)] = f2bf(val);
    }
  }
}

// ---------------- launch ----------------
extern "C" void kernel_launch(void* const* d_in, const int* in_sizes, int n_in,
                              void* d_out, int out_size, void* d_ws, size_t ws_size,
                              hipStream_t stream) {
  const float* x = (const float*)d_in[0];
  const float* Wqkv = (const float*)d_in[1];
  const float* bqkv = (const float*)d_in[2];
  const float* Wout = (const float*)d_in[3];
  const float* bout = (const float*)d_in[4];
  float* out = (float*)d_out;

  char* p = (char*)d_ws;
  float* ct = (float*)p; p += (size_t)65536 * 4;
  float* st = (float*)p; p += (size_t)65536 * 4;
  u16* Xb  = (u16*)p; p += (size_t)8388608 * 2;
  u16* Wqb = (u16*)p; p += (size_t)3145728 * 2;
  u16* Wob = (u16*)p; p += (size_t)1048576 * 2;
  u16* Qw  = (u16*)p; p += (size_t)8388608 * 2;
  u16* Kw  = (u16*)p; p += (size_t)8388608 * 2;
  u16* Vw  = (u16*)p; p += (size_t)8388608 * 2;   // transposed [b,h,d,s]
  u16* AO  = (u16*)p; p += (size_t)8388608 * 2;

  cast_bf16_kernel<<<8192, 256, 0, stream>>>(x, Xb, 8388608);
  cast_bf16_kernel<<<3072, 256, 0, stream>>>(Wqkv, Wqb, 3145728);
  cast_bf16_kernel<<<1024, 256, 0, stream>>>(Wout, Wob, 1048576);
  rope_table_kernel<<<256, 256, 0, stream>>>(ct, st);

  gemm128<0><<<dim3(24, 64), 256, 0, stream>>>(Xb, Wqb, bqkv, Qw, Kw, Vw, ct, st, nullptr);
  attn_kernel<<<dim3(32, 64), 256, 0, stream>>>(Qw, Kw, Vw, AO);
  gemm128<1><<<dim3(8, 64), 256, 0, stream>>>(AO, Wob, bout, nullptr, nullptr, nullptr, nullptr, nullptr, out);
}